// Round 4
// baseline (229.664 us; speedup 1.0000x reference)
//
#include <hip/hip_runtime.h>
#include <hip/hip_bf16.h>

#define NN 16384
#define TT 4
#define HH 64
#define NT (NN * TT)
#define CAPH 64   // bucket capacity per (node, set, src-half); Poisson(8) => P(>64) ~ 0
#define NEG_SLOPE 0.2f
#define LN_EPS 1e-5f

typedef __attribute__((ext_vector_type(8))) short short8;   // 8 bf16 (4 VGPRs)
typedef __attribute__((ext_vector_type(4))) float f32x4;    // MFMA accumulator

__device__ __forceinline__ float bf2f(unsigned short u) {
    return __uint_as_float((unsigned)u << 16);
}
// f32 -> bf16 RNE, layout-independent
__device__ __forceinline__ unsigned short f2bf(float f) {
    unsigned u = __float_as_uint(f);
    return (unsigned short)((u + 0x7FFF + ((u >> 16) & 1)) >> 16);
}

// ---------------- bucket-CSR build: [set][src-half][dest] buckets ----------------
// Partitioning each dest's edge list by SOURCE half (src<8192 vs >=8192) makes the
// aggregate's gather working set per phase a 4MB slice == one XCD L2.

__global__ void zero_kernel(int* __restrict__ a, int n) {
    int i = blockIdx.x * blockDim.x + threadIdx.x;
    if (i < n) a[i] = 0;
}

__global__ void scatter4_kernel(const int* __restrict__ ei_s, const int* __restrict__ ei_f,
                                int* __restrict__ cnt4, int* __restrict__ col4, int E) {
    int e = blockIdx.x * blockDim.x + threadIdx.x;
    int src, d, set;
    if (e < E) {
        set = 0; src = ei_s[e]; d = ei_s[E + e];
    } else {
        e -= E;
        if (e >= E) return;
        set = 1; src = ei_f[e]; d = ei_f[E + e];
    }
    int half = src >> 13;                    // src / 8192
    int p = set * 2 + half;                  // phase id 0..3
    int pos = atomicAdd(&cnt4[p * NN + d], 1);
    if (pos < CAPH) col4[((long)p * NN + d) * CAPH + pos] = src;
}

// ---------------- one-time W fragment pack ----------------
// Converts the four 64x64 f32 weight matrices into bf16 MFMA B-fragment layout:
// wpack[mat][ (c*2+ks)*64 + lane ] = short8 of W[k=ks*32+quad*8+j][n=c*16+m].
// Transform then loads B-frags with 8 coalesced 16B loads instead of 128
// scattered 4B loads + 128 f2bf per thread.

__global__ __launch_bounds__(256) void packw_kernel(
    const float* __restrict__ W0s_, const float* __restrict__ W0f_,
    const float* __restrict__ W1s_, const float* __restrict__ W1f_,
    short8* __restrict__ wpack) {
    int id = blockIdx.x * 256 + threadIdx.x;   // [0, 2048)
    int mat = id >> 9;
    int slot = id & 511;
    int lane = slot & 63;
    int cks = slot >> 6;
    int c = cks >> 1, ks = cks & 1;
    int m = lane & 15, quad = lane >> 4;
    const float* W = (mat == 0) ? W0s_ : (mat == 1) ? W0f_ : (mat == 2) ? W1s_ : W1f_;
    short8 v;
#pragma unroll
    for (int j = 0; j < 8; j++) {
        int k = ks * 32 + quad * 8 + j;
        int n = c * 16 + m;
        v[j] = (short)f2bf(W[k * 64 + n]);
    }
    wpack[id] = v;
}

// ------- fused dual transform via MFMA: h_s = x*Ws, h_f = x*Wf + exp-scores ------
// v_mfma_f32_16x16x32_bf16. A-frag: A[m=lane&15][k=quad*8+j]. B-frag (KxN):
// B[k=quad*8+j][n=lane&15]. C/D: col=lane&15, row=quad*4+reg.
// Wave = 32 rows (2 row-tiles); block = 4 waves = 128 rows; grid = NT/128.
// Epilogue stores esc = exp(leakyrelu(score)) so the aggregate never runs exp
// (softmax here is single-pass without max subtraction; logits are O(+-8)).

__global__ __launch_bounds__(256) void transform2_kernel(
    const float4* __restrict__ x4,
    const short8* __restrict__ wp_s, const float* __restrict__ as_,
    const short8* __restrict__ wp_f, const float* __restrict__ af,
    unsigned short* __restrict__ h_s, float* __restrict__ esc_s,
    unsigned short* __restrict__ h_f, float* __restrict__ esc_f) {
    const int lane = threadIdx.x & 63;
    const int wv = threadIdx.x >> 6;
    const int m = lane & 15;
    const int quad = lane >> 4;

    short8 Bs[4][2], Bf[4][2];
#pragma unroll
    for (int c = 0; c < 4; c++) {
#pragma unroll
        for (int ks = 0; ks < 2; ks++) {
            Bs[c][ks] = wp_s[(c * 2 + ks) * 64 + lane];
            Bf[c][ks] = wp_f[(c * 2 + ks) * 64 + lane];
        }
    }
    float a_s[4], a_f[4];
#pragma unroll
    for (int c = 0; c < 4; c++) { a_s[c] = as_[c * 16 + m]; a_f[c] = af[c * 16 + m]; }

    const int rowbase = blockIdx.x * 128 + wv * 32;
#pragma unroll
    for (int rt = 0; rt < 2; rt++) {
        const int row0 = rowbase + rt * 16;
        const long xbase = (long)(row0 + m) * 16 + quad * 2;
        float4 xa = x4[xbase];
        float4 xb = x4[xbase + 1];
        float4 xc = x4[xbase + 8];
        float4 xd = x4[xbase + 9];
        short8 A0, A1;
        A0[0] = (short)f2bf(xa.x); A0[1] = (short)f2bf(xa.y);
        A0[2] = (short)f2bf(xa.z); A0[3] = (short)f2bf(xa.w);
        A0[4] = (short)f2bf(xb.x); A0[5] = (short)f2bf(xb.y);
        A0[6] = (short)f2bf(xb.z); A0[7] = (short)f2bf(xb.w);
        A1[0] = (short)f2bf(xc.x); A1[1] = (short)f2bf(xc.y);
        A1[2] = (short)f2bf(xc.z); A1[3] = (short)f2bf(xc.w);
        A1[4] = (short)f2bf(xd.x); A1[5] = (short)f2bf(xd.y);
        A1[6] = (short)f2bf(xd.z); A1[7] = (short)f2bf(xd.w);

        f32x4 accs[4], accf[4];
#pragma unroll
        for (int c = 0; c < 4; c++) {
            accs[c] = (f32x4){0.f, 0.f, 0.f, 0.f};
            accf[c] = (f32x4){0.f, 0.f, 0.f, 0.f};
        }
#pragma unroll
        for (int c = 0; c < 4; c++) {
            accs[c] = __builtin_amdgcn_mfma_f32_16x16x32_bf16(A0, Bs[c][0], accs[c], 0, 0, 0);
            accs[c] = __builtin_amdgcn_mfma_f32_16x16x32_bf16(A1, Bs[c][1], accs[c], 0, 0, 0);
            accf[c] = __builtin_amdgcn_mfma_f32_16x16x32_bf16(A0, Bf[c][0], accf[c], 0, 0, 0);
            accf[c] = __builtin_amdgcn_mfma_f32_16x16x32_bf16(A1, Bf[c][1], accf[c], 0, 0, 0);
        }
#pragma unroll
        for (int reg = 0; reg < 4; reg++) {
            const int row = row0 + quad * 4 + reg;
            float ps = 0.f, pf = 0.f;
#pragma unroll
            for (int c = 0; c < 4; c++) {
                h_s[(long)row * 64 + c * 16 + m] = f2bf(accs[c][reg]);
                h_f[(long)row * 64 + c * 16 + m] = f2bf(accf[c][reg]);
                ps = fmaf(accs[c][reg], a_s[c], ps);
                pf = fmaf(accf[c][reg], a_f[c], pf);
            }
#pragma unroll
            for (int off = 1; off < 16; off <<= 1) {
                ps += __shfl_xor(ps, off, 64);
                pf += __shfl_xor(pf, off, 64);
            }
            if (m == 0) {
                float ls = (ps > 0.f) ? ps : NEG_SLOPE * ps;  // LeakyReLU folded in
                float lf = (pf > 0.f) ? pf : NEG_SLOPE * pf;
                esc_s[row] = __expf(ls);  // pre-exponentiated score
                esc_f[row] = __expf(lf);
            }
        }
    }
}

// ---------------- attention aggregation, src-half phased ----------------
// Wave = 1 node. 4 phases in FIXED global order: (set s, src<8192), (s, src>=8192),
// (f, src<8192), (f, src>=8192). Each phase's h slice is 4MB == one XCD L2, and all
// concurrently-running waves are in (approximately) the same phase -> gathers become
// L2 hits instead of 3.3TB/s-capped fabric/L3 traffic. Accumulators persist in
// registers across phases. Index vectors for all 4 phases preloaded upfront
// (coalesced 64-wide) so per-phase chains start immediately via v_readlane.
// lane: t = lane>>4, channels 4*(lane&15)..+3.

__device__ __forceinline__ void agg_phase(const ushort4* __restrict__ h4,
                                          const float* __restrict__ esc,
                                          int idx, int c, int t, int lane,
                                          float& den, float& ax, float& ay,
                                          float& az, float& aw) {
    const int nb = (c + 7) >> 3;
    for (int it = 0; it < nb; ++it) {
        const int j = it << 3;
        int s[8];
        float e[8];
        ushort4 h[8];
#pragma unroll
        for (int u = 0; u < 8; u++) s[u] = __builtin_amdgcn_readlane(idx, j + u);
#pragma unroll
        for (int u = 0; u < 8; u++) h[u] = h4[s[u] * 64 + lane];
#pragma unroll
        for (int u = 0; u < 8; u++) e[u] = esc[s[u] * 4 + t];
#pragma unroll
        for (int u = 0; u < 8; u++) {
            float w = (j + u < c) ? e[u] : 0.f;
            den += w;
            ax = fmaf(w, bf2f(h[u].x), ax);
            ay = fmaf(w, bf2f(h[u].y), ay);
            az = fmaf(w, bf2f(h[u].z), az);
            aw = fmaf(w, bf2f(h[u].w), aw);
        }
    }
}

__global__ __launch_bounds__(256) void aggregate_kernel(
    const float4* __restrict__ x4,
    const ushort4* __restrict__ hs4, const float* __restrict__ escs,
    const ushort4* __restrict__ hf4, const float* __restrict__ escf,
    const int* __restrict__ cnt4, const int* __restrict__ col4,
    const float4* __restrict__ g4, const float4* __restrict__ b4,
    float4* __restrict__ out4) {
    const int wv = threadIdx.x >> 6;
    const int lane = threadIdx.x & 63;
    const int n = blockIdx.x * 4 + wv;
    const int t = lane >> 4;
    const int ci = lane & 15;

    // preload counts + index vectors for all 4 phases (independent, coalesced)
    int cc[4], idx[4];
#pragma unroll
    for (int p = 0; p < 4; p++) {
        int cv = cnt4[p * NN + n];
        if (cv > CAPH) cv = CAPH;
        cc[p] = __builtin_amdgcn_readfirstlane(cv);
        idx[p] = col4[((long)p * NN + n) * CAPH + lane];
        if (lane >= cc[p]) idx[p] = 0;  // masked lanes -> node 0 (hot line, weight 0)
    }

    float dS = 0.f, sx = 0.f, sy = 0.f, sz = 0.f, sw = 0.f;
    float dF = 0.f, fx = 0.f, fy = 0.f, fz = 0.f, fw = 0.f;

    agg_phase(hs4, escs, idx[0], cc[0], t, lane, dS, sx, sy, sz, sw);
    agg_phase(hs4, escs, idx[1], cc[1], t, lane, dS, sx, sy, sz, sw);
    agg_phase(hf4, escf, idx[2], cc[2], t, lane, dF, fx, fy, fz, fw);
    agg_phase(hf4, escf, idx[3], cc[3], t, lane, dF, fx, fy, fz, fw);

    float msx = 0.f, msy = 0.f, msz = 0.f, msw = 0.f;
    if (dS > 0.f) {
        float r = 1.f / dS;
        msx = sx * r; msy = sy * r; msz = sz * r; msw = sw * r;
    }
    float mfx = 0.f, mfy = 0.f, mfz = 0.f, mfw = 0.f;
    if (dF > 0.f) {
        float r = 1.f / dF;
        mfx = fx * r; mfy = fy * r; mfz = fz * r; mfw = fw * r;
    }

    float4 xv = x4[(long)n * 64 + lane];  // x[n][t][4*ci..+3]
    float v0 = xv.x + 0.5f * (msx + mfx);
    float v1 = xv.y + 0.5f * (msy + mfy);
    float v2 = xv.z + 0.5f * (msz + mfz);
    float v3 = xv.w + 0.5f * (msw + mfw);

    // LayerNorm over H=64: 16-lane group (same t), 4 values/lane
    float sum = (v0 + v1) + (v2 + v3);
#pragma unroll
    for (int off = 1; off < 16; off <<= 1) sum += __shfl_xor(sum, off, 64);
    float mu = sum * (1.f / 64.f);
    float d0 = v0 - mu, d1 = v1 - mu, d2 = v2 - mu, d3 = v3 - mu;
    float var = (d0 * d0 + d1 * d1) + (d2 * d2 + d3 * d3);
#pragma unroll
    for (int off = 1; off < 16; off <<= 1) var += __shfl_xor(var, off, 64);
    var *= (1.f / 64.f);
    float inv = rsqrtf(var + LN_EPS);
    float4 gv = g4[ci], bv = b4[ci];
    float4 o;
    o.x = d0 * inv * gv.x + bv.x;
    o.y = d1 * inv * gv.y + bv.y;
    o.z = d2 * inv * gv.z + bv.z;
    o.w = d3 * inv * gv.w + bv.w;
    out4[(long)n * 64 + lane] = o;
}

// ---------------- launch ----------------

extern "C" void kernel_launch(void* const* d_in, const int* in_sizes, int n_in,
                              void* d_out, int out_size, void* d_ws, size_t ws_size,
                              hipStream_t stream) {
    const float* pred = (const float*)d_in[0];
    const int* ei_s = (const int*)d_in[1];
    const int* ei_f = (const int*)d_in[2];
    const float* W0s = (const float*)d_in[3];
    const float* a0s = (const float*)d_in[4];
    const float* W0f = (const float*)d_in[5];
    const float* a0f = (const float*)d_in[6];
    const float* g0  = (const float*)d_in[7];
    const float* b0  = (const float*)d_in[8];
    const float* W1s = (const float*)d_in[9];
    const float* a1s = (const float*)d_in[10];
    const float* W1f = (const float*)d_in[11];
    const float* a1f = (const float*)d_in[12];
    const float* g1  = (const float*)d_in[13];
    const float* b1  = (const float*)d_in[14];
    const int E = in_sizes[1] / 2;  // 262144

    // workspace bump allocator (~51 MB)
    char* ws = (char*)d_ws;
    auto alloc = [&](size_t bytes) {
        char* p = ws;
        ws += (bytes + 255) & ~(size_t)255;
        return p;
    };
    int* cnt4 = (int*)alloc((size_t)4 * NN * sizeof(int));
    int* col4 = (int*)alloc((size_t)4 * NN * CAPH * sizeof(int));
    short8* wpack = (short8*)alloc((size_t)4 * 512 * sizeof(short8));
    unsigned short* h_s = (unsigned short*)alloc((size_t)NT * HH * sizeof(unsigned short));
    unsigned short* h_f = (unsigned short*)alloc((size_t)NT * HH * sizeof(unsigned short));
    float* esc_s = (float*)alloc((size_t)NT * sizeof(float));
    float* esc_f = (float*)alloc((size_t)NT * sizeof(float));
    float* x_mid = (float*)alloc((size_t)NT * HH * sizeof(float));

    const int EB = (E + 255) / 256;

    // one-time weight fragment pack (independent of CSR build)
    packw_kernel<<<8, 256, 0, stream>>>(W0s, W0f, W1s, W1f, wpack);

    // bucket-CSR build: [set][src-half][dest]; cnt4 ends as per-bucket degrees
    zero_kernel<<<(4 * NN) / 256, 256, 0, stream>>>(cnt4, 4 * NN);
    scatter4_kernel<<<2 * EB, 256, 0, stream>>>(ei_s, ei_f, cnt4, col4, E);

    // layer 0
    transform2_kernel<<<NT / 128, 256, 0, stream>>>(
        (const float4*)pred, wpack, a0s, wpack + 512, a0f, h_s, esc_s, h_f, esc_f);
    aggregate_kernel<<<NN / 4, 256, 0, stream>>>(
        (const float4*)pred, (const ushort4*)h_s, esc_s,
        (const ushort4*)h_f, esc_f, cnt4, col4,
        (const float4*)g0, (const float4*)b0, (float4*)x_mid);

    // layer 1
    transform2_kernel<<<NT / 128, 256, 0, stream>>>(
        (const float4*)x_mid, wpack + 1024, a1s, wpack + 1536, a1f, h_s, esc_s, h_f, esc_f);
    aggregate_kernel<<<NN / 4, 256, 0, stream>>>(
        (const float4*)x_mid, (const ushort4*)h_s, esc_s,
        (const ushort4*)h_f, esc_f, cnt4, col4,
        (const float4*)g1, (const float4*)b1, (float4*)d_out);
}